// Round 13
// baseline (771.579 us; speedup 1.0000x reference)
//
#include <hip/hip_runtime.h>

// Problem constants (B=4, S=2048 -> T=8192)
#define T_TOKENS 8192
#define H_DIM 1024
#define F_DIM 4096
#define E_NUM 8

typedef unsigned short u16;
typedef __attribute__((ext_vector_type(8))) short bf16x8;
typedef __attribute__((ext_vector_type(4))) float f32x4;

__device__ __forceinline__ u16 f2bf(float f) {
  union { float f; unsigned int u; } v; v.f = f;
  unsigned int r = v.u + 0x7fffu + ((v.u >> 16) & 1u);
  return (u16)(r >> 16);
}
__device__ __forceinline__ float bf2f(u16 u) {
  union { unsigned int u; float f; } v; v.u = ((unsigned int)u) << 16;
  return v.f;
}

#define GLOAD_LDS(g, l)                                                        \
  __builtin_amdgcn_global_load_lds(                                            \
      (const __attribute__((address_space(1))) void*)(g),                      \
      (__attribute__((address_space(3))) void*)(l), 16, 0, 0)

// ---------------- fp32 -> bf16 convert (vectorized) ----------------
__global__ void cvt_kernel(const float* __restrict__ in, u16* __restrict__ out,
                           int n4) {
  int i = blockIdx.x * blockDim.x + threadIdx.x;
  int stride = gridDim.x * blockDim.x;
  for (; i < n4; i += stride) {
    float4 v = ((const float4*)in)[i];
    ushort4 o;
    o.x = f2bf(v.x); o.y = f2bf(v.y); o.z = f2bf(v.z); o.w = f2bf(v.w);
    ((ushort4*)out)[i] = o;
  }
}

// ------- router: logits + softmax + top2 + renorm, fused x->bf16 cvt -------
__global__ void router_kernel(const float* __restrict__ x,
                              const float* __restrict__ gw,
                              u16* __restrict__ xb,
                              float* __restrict__ logits_out,
                              int* __restrict__ sel, float* __restrict__ selw) {
  int wid = threadIdx.x >> 6;
  int lane = threadIdx.x & 63;
  int t = blockIdx.x * 4 + wid;
  const float4* xr = (const float4*)(x + (size_t)t * H_DIM);
  ushort4* xbr = (ushort4*)(xb + (size_t)t * H_DIM);
  float acc[E_NUM];
#pragma unroll
  for (int e = 0; e < E_NUM; e++) acc[e] = 0.f;
#pragma unroll
  for (int it = 0; it < H_DIM / 256; it++) {
    int i4 = it * 64 + lane;
    float4 v = xr[i4];
    ushort4 o;
    o.x = f2bf(v.x); o.y = f2bf(v.y); o.z = f2bf(v.z); o.w = f2bf(v.w);
    xbr[i4] = o;
#pragma unroll
    for (int e = 0; e < E_NUM; e++) {
      float4 g = ((const float4*)(gw + (size_t)e * H_DIM))[i4];
      acc[e] += v.x * g.x + v.y * g.y + v.z * g.z + v.w * g.w;
    }
  }
#pragma unroll
  for (int off = 32; off > 0; off >>= 1) {
#pragma unroll
    for (int e = 0; e < E_NUM; e++) acc[e] += __shfl_xor(acc[e], off);
  }
  if (lane < E_NUM) logits_out[(size_t)t * E_NUM + lane] = acc[lane];
  if (lane == 0) {
    float m = acc[0];
#pragma unroll
    for (int e = 1; e < E_NUM; e++) m = fmaxf(m, acc[e]);
    float p[E_NUM];
#pragma unroll
    for (int e = 0; e < E_NUM; e++) p[e] = expf(acc[e] - m);
    int e0 = 0; float p0 = p[0];
#pragma unroll
    for (int e = 1; e < E_NUM; e++) if (p[e] > p0) { p0 = p[e]; e0 = e; }
    int e1 = -1; float p1 = -1.f;
#pragma unroll
    for (int e = 0; e < E_NUM; e++)
      if (e != e0 && p[e] > p1) { p1 = p[e]; e1 = e; }
    float inv = 1.f / (p0 + p1);  // softmax denom cancels in renorm
    sel[t * 2] = e0; sel[t * 2 + 1] = e1;
    selw[t * 2] = p0 * inv; selw[t * 2 + 1] = p1 * inv;
  }
}

// ---------------- scatter: build per-expert pair lists ----------------
__global__ void scatter_kernel(const int* __restrict__ sel,
                               const float* __restrict__ selw,
                               int* __restrict__ cnt, int* __restrict__ list,
                               float* __restrict__ wpair) {
  int t = blockIdx.x * blockDim.x + threadIdx.x;
  if (t >= T_TOKENS) return;
#pragma unroll
  for (int k = 0; k < 2; k++) {
    int e = sel[t * 2 + k];
    int pos = atomicAdd(&cnt[e], 1);
    list[e * T_TOKENS + pos] = t * 2 + k;
    wpair[t * 2 + k] = selw[t * 2 + k];
  }
}

// ---------------- exclusive scan of expert counts (8 values) ----------------
__global__ void scan_kernel(const int* __restrict__ cnt, int* __restrict__ base) {
  if (threadIdx.x == 0) {
    int b = 0;
#pragma unroll
    for (int e = 0; e < E_NUM; e++) { base[e] = b; b += cnt[e]; }
  }
}

// ---- GEMM1: inter[base[e]+pos] = silu(x@w1^T) * (x@w3^T), compacted bf16 ---
// R8/R9-proven: 128x128 tile, BK=64, 512 thr / 8 waves, wave-tile 32Mx64N.
// VGPR 64 + 64 AGPR -> 4 waves/SIMD, occ 41%, 334us.
__global__ __launch_bounds__(512, 4) void gemm1_kernel(
    const u16* __restrict__ xb, const u16* __restrict__ w1b,
    const u16* __restrict__ w3b, const int* __restrict__ cnt,
    const int* __restrict__ base, const int* __restrict__ list,
    u16* __restrict__ inter) {
  int e = blockIdx.z;
  int ne = cnt[e];
  int m0 = blockIdx.y * 128;
  if (m0 >= ne) return;
  int nb = blockIdx.x;
  int cbase = base[e];

  __shared__ u16 al[128 * 64];
  __shared__ u16 b1l[128 * 64];
  __shared__ u16 b3l[128 * 64];
  __shared__ int s_pair[128];

  int tid = threadIdx.x;
  if (tid < 128) {
    int idx = m0 + tid;
    s_pair[tid] = list[e * T_TOKENS + (idx < ne ? idx : 0)];
  }
  __syncthreads();

  // staging: slot L = tid + 512*r covers row L>>3, 16B chunk L&7; source
  // chunk XOR-swizzled by row&7 so linear LDS dest ends up swizzled.
  const u16 *ab[2], *b1b[2], *b3b[2];
#pragma unroll
  for (int r = 0; r < 2; r++) {
    int L = tid + 512 * r;
    int row = L >> 3;
    int sc = (((L & 7) ^ (row & 7)) << 3);
    ab[r] = xb + (size_t)(s_pair[row] >> 1) * H_DIM + sc;
    b1b[r] = w1b + ((size_t)e * F_DIM + (size_t)nb * 128 + row) * H_DIM + sc;
    b3b[r] = w3b + ((size_t)e * F_DIM + (size_t)nb * 128 + row) * H_DIM + sc;
  }

  int lane = tid & 63, w = tid >> 6;
  int wm = (w & 3) * 32;   // 4 waves along M, 32 rows each
  int wn = (w >> 2) * 64;  // 2 waves along N, 64 cols each
  int fr = lane & 15, q0 = lane >> 4;

  f32x4 zero = {0.f, 0.f, 0.f, 0.f};
  f32x4 acc1[2][4], acc3[2][4];
#pragma unroll
  for (int i = 0; i < 2; i++)
#pragma unroll
    for (int j = 0; j < 4; j++) { acc1[i][j] = zero; acc3[i][j] = zero; }

  for (int kt = 0; kt < H_DIM; kt += 64) {
#pragma unroll
    for (int r = 0; r < 2; r++) {
      int c8 = (r * 512 + tid) * 8;
      GLOAD_LDS(ab[r] + kt, &al[c8]);
      GLOAD_LDS(b1b[r] + kt, &b1l[c8]);
      GLOAD_LDS(b3b[r] + kt, &b3l[c8]);
    }
    __syncthreads();
#pragma unroll
    for (int kk = 0; kk < 2; kk++) {
      int q = kk * 4 + q0;
      bf16x8 af[2], bf[4];
#pragma unroll
      for (int i = 0; i < 2; i++) {
        int row = wm + i * 16 + fr;
        af[i] = *(const bf16x8*)&al[row * 64 + ((q ^ (row & 7)) << 3)];
      }
#pragma unroll
      for (int j = 0; j < 4; j++) {
        int row = wn + j * 16 + fr;
        bf[j] = *(const bf16x8*)&b1l[row * 64 + ((q ^ (row & 7)) << 3)];
      }
#pragma unroll
      for (int i = 0; i < 2; i++)
#pragma unroll
        for (int j = 0; j < 4; j++)
          acc1[i][j] = __builtin_amdgcn_mfma_f32_16x16x32_bf16(
              af[i], bf[j], acc1[i][j], 0, 0, 0);
#pragma unroll
      for (int j = 0; j < 4; j++) {
        int row = wn + j * 16 + fr;
        bf[j] = *(const bf16x8*)&b3l[row * 64 + ((q ^ (row & 7)) << 3)];
      }
#pragma unroll
      for (int i = 0; i < 2; i++)
#pragma unroll
        for (int j = 0; j < 4; j++)
          acc3[i][j] = __builtin_amdgcn_mfma_f32_16x16x32_bf16(
              af[i], bf[j], acc3[i][j], 0, 0, 0);
    }
    __syncthreads();
  }

  // epilogue: SwiGLU, write compacted inter rows
#pragma unroll
  for (int i = 0; i < 2; i++) {
#pragma unroll
    for (int r = 0; r < 4; r++) {
      int ml = wm + i * 16 + q0 * 4 + r;
      if (m0 + ml < ne) {
        size_t basei =
            (size_t)(cbase + m0 + ml) * F_DIM + (size_t)nb * 128 + wn + fr;
#pragma unroll
        for (int j = 0; j < 4; j++) {
          float h1 = acc1[i][j][r], h3 = acc3[i][j][r];
          float v = h1 / (1.f + __expf(-h1)) * h3;
          inter[basei + j * 16] = f2bf(v);
        }
      }
    }
  }
}

// ---- GEMM2: y[pair] = inter[compact] @ w2^T (plain bf16 stores) ----
// NEW: exact gemm1 structure — dual-B (two 128-col groups of w2 share the
// A-fragment: 3 tiles staged per 256 block-MFMAs) + 512 thr / 8 waves /
// 32Mx64N wave-tile (64 acc f32 -> 4 waves/SIMD). Grid 4x64x8 -> ~512
// active blocks x 8 waves = 16 waves/CU = exactly steady-state capacity.
__global__ __launch_bounds__(512, 4) void gemm2_kernel(
    const u16* __restrict__ inter, const u16* __restrict__ w2b,
    const int* __restrict__ cnt, const int* __restrict__ base,
    const int* __restrict__ list, u16* __restrict__ y) {
  int e = blockIdx.z;
  int ne = cnt[e];
  int m0 = blockIdx.y * 128;
  if (m0 >= ne) return;
  int nb = blockIdx.x;  // H / 256 = 4
  int cbase = base[e];

  __shared__ u16 al[128 * 64];
  __shared__ u16 bl0[128 * 64];
  __shared__ u16 bl1[128 * 64];
  __shared__ int s_pair[128];

  int tid = threadIdx.x;
  if (tid < 128) {
    int idx = m0 + tid;
    s_pair[tid] = list[e * T_TOKENS + (idx < ne ? idx : 0)];
  }
  __syncthreads();

  const u16 *ab[2], *b0b[2], *b1b[2];
#pragma unroll
  for (int r = 0; r < 2; r++) {
    int L = tid + 512 * r;
    int row = L >> 3;
    int sc = (((L & 7) ^ (row & 7)) << 3);
    int cr = m0 + row;
    if (cr >= ne) cr = 0;  // clamp within expert (stores guarded anyway)
    ab[r] = inter + (size_t)(cbase + cr) * F_DIM + sc;
    b0b[r] = w2b + ((size_t)e * H_DIM + (size_t)nb * 256 + row) * F_DIM + sc;
    b1b[r] =
        w2b + ((size_t)e * H_DIM + (size_t)nb * 256 + 128 + row) * F_DIM + sc;
  }

  int lane = tid & 63, w = tid >> 6;
  int wm = (w & 3) * 32;   // 4 waves along M
  int wn = (w >> 2) * 64;  // 2 waves along N (within each 128-col group)
  int fr = lane & 15, q0 = lane >> 4;

  f32x4 zero = {0.f, 0.f, 0.f, 0.f};
  f32x4 acc0[2][4], acc1[2][4];
#pragma unroll
  for (int i = 0; i < 2; i++)
#pragma unroll
    for (int j = 0; j < 4; j++) { acc0[i][j] = zero; acc1[i][j] = zero; }

  for (int kt = 0; kt < F_DIM; kt += 64) {
#pragma unroll
    for (int r = 0; r < 2; r++) {
      int c8 = (r * 512 + tid) * 8;
      GLOAD_LDS(ab[r] + kt, &al[c8]);
      GLOAD_LDS(b0b[r] + kt, &bl0[c8]);
      GLOAD_LDS(b1b[r] + kt, &bl1[c8]);
    }
    __syncthreads();
#pragma unroll
    for (int kk = 0; kk < 2; kk++) {
      int q = kk * 4 + q0;
      bf16x8 af[2], bf[4];
#pragma unroll
      for (int i = 0; i < 2; i++) {
        int row = wm + i * 16 + fr;
        af[i] = *(const bf16x8*)&al[row * 64 + ((q ^ (row & 7)) << 3)];
      }
#pragma unroll
      for (int j = 0; j < 4; j++) {
        int row = wn + j * 16 + fr;
        bf[j] = *(const bf16x8*)&bl0[row * 64 + ((q ^ (row & 7)) << 3)];
      }
#pragma unroll
      for (int i = 0; i < 2; i++)
#pragma unroll
        for (int j = 0; j < 4; j++)
          acc0[i][j] = __builtin_amdgcn_mfma_f32_16x16x32_bf16(
              af[i], bf[j], acc0[i][j], 0, 0, 0);
#pragma unroll
      for (int j = 0; j < 4; j++) {
        int row = wn + j * 16 + fr;
        bf[j] = *(const bf16x8*)&bl1[row * 64 + ((q ^ (row & 7)) << 3)];
      }
#pragma unroll
      for (int i = 0; i < 2; i++)
#pragma unroll
        for (int j = 0; j < 4; j++)
          acc1[i][j] = __builtin_amdgcn_mfma_f32_16x16x32_bf16(
              af[i], bf[j], acc1[i][j], 0, 0, 0);
    }
    __syncthreads();
  }

  // epilogue: plain bf16 stores into pair-indexed y (one writer per row)
#pragma unroll
  for (int i = 0; i < 2; i++) {
#pragma unroll
    for (int r = 0; r < 4; r++) {
      int ml = wm + i * 16 + q0 * 4 + r;
      if (m0 + ml < ne) {
        u16* yb = y + (size_t)s_pair[ml] * H_DIM + (size_t)nb * 256 + wn + fr;
#pragma unroll
        for (int j = 0; j < 4; j++) {
          yb[j * 16] = f2bf(acc0[i][j][r]);
          yb[128 + j * 16] = f2bf(acc1[i][j][r]);
        }
      }
    }
  }
}

// ---- combine: out[t] = w0 * y[2t] + w1 * y[2t+1] (fp32 out) ----
__global__ void combine_kernel(const u16* __restrict__ y,
                               const float* __restrict__ wpair,
                               float* __restrict__ out) {
  int t = blockIdx.x;
  float w0 = wpair[t * 2], w1 = wpair[t * 2 + 1];
  const ushort4* y0 = (const ushort4*)(y + (size_t)t * 2 * H_DIM);
  const ushort4* y1 = (const ushort4*)(y + ((size_t)t * 2 + 1) * H_DIM);
  float4* o = (float4*)(out + (size_t)t * H_DIM);
  int i = threadIdx.x;  // 256 threads x 4 elems = 1024 = H_DIM
  ushort4 a = y0[i], b = y1[i];
  float4 r;
  r.x = w0 * bf2f(a.x) + w1 * bf2f(b.x);
  r.y = w0 * bf2f(a.y) + w1 * bf2f(b.y);
  r.z = w0 * bf2f(a.z) + w1 * bf2f(b.z);
  r.w = w0 * bf2f(a.w) + w1 * bf2f(b.w);
  o[i] = r;
}

// ---------------- workspace layout (bytes) ----------------
#define XB_OFF 0UL
#define W1B_OFF (XB_OFF + (size_t)T_TOKENS * H_DIM * 2)
#define W3B_OFF (W1B_OFF + (size_t)E_NUM * F_DIM * H_DIM * 2)
#define W2B_OFF (W3B_OFF + (size_t)E_NUM * F_DIM * H_DIM * 2)
#define INTER_OFF (W2B_OFF + (size_t)E_NUM * F_DIM * H_DIM * 2)
#define CNT_OFF (INTER_OFF + (size_t)2 * T_TOKENS * F_DIM * 2)
#define BASE_OFF (CNT_OFF + 64)
#define LIST_OFF (BASE_OFF + 192)
#define WPAIR_OFF (LIST_OFF + (size_t)E_NUM * T_TOKENS * 4)
#define SEL_OFF (WPAIR_OFF + (size_t)2 * T_TOKENS * 4)
#define SELW_OFF (SEL_OFF + (size_t)2 * T_TOKENS * 4)
// y (2T x H bf16, 32 MiB) aliases the dead w1b region (stream-ordered).
#define Y_OFF W1B_OFF

extern "C" void kernel_launch(void* const* d_in, const int* in_sizes, int n_in,
                              void* d_out, int out_size, void* d_ws,
                              size_t ws_size, hipStream_t stream) {
  const float* x = (const float*)d_in[0];
  const float* gw = (const float*)d_in[1];
  const float* w1 = (const float*)d_in[2];
  const float* w2 = (const float*)d_in[3];
  const float* w3 = (const float*)d_in[4];
  float* out = (float*)d_out;
  float* logits_out = out + (size_t)T_TOKENS * H_DIM;

  char* ws = (char*)d_ws;
  u16* xb = (u16*)(ws + XB_OFF);
  u16* w1b = (u16*)(ws + W1B_OFF);
  u16* w3b = (u16*)(ws + W3B_OFF);
  u16* w2b = (u16*)(ws + W2B_OFF);
  u16* inter = (u16*)(ws + INTER_OFF);
  u16* y = (u16*)(ws + Y_OFF);
  int* cnt = (int*)(ws + CNT_OFF);
  int* base = (int*)(ws + BASE_OFF);
  int* list = (int*)(ws + LIST_OFF);
  float* wpair = (float*)(ws + WPAIR_OFF);
  int* sel = (int*)(ws + SEL_OFF);
  float* selw = (float*)(ws + SELW_OFF);

  hipMemsetAsync(cnt, 0, 64, stream);

  cvt_kernel<<<2048, 256, 0, stream>>>(w1, w1b, E_NUM * F_DIM * H_DIM / 4);
  cvt_kernel<<<2048, 256, 0, stream>>>(w3, w3b, E_NUM * F_DIM * H_DIM / 4);
  cvt_kernel<<<2048, 256, 0, stream>>>(w2, w2b, E_NUM * F_DIM * H_DIM / 4);

  router_kernel<<<T_TOKENS / 4, 256, 0, stream>>>(x, gw, xb, logits_out, sel,
                                                  selw);
  scatter_kernel<<<T_TOKENS / 256, 256, 0, stream>>>(sel, selw, cnt, list,
                                                     wpair);
  scan_kernel<<<1, 64, 0, stream>>>(cnt, base);

  gemm1_kernel<<<dim3(F_DIM / 128, T_TOKENS / 128, E_NUM), 512, 0, stream>>>(
      xb, w1b, w3b, cnt, base, list, inter);
  gemm2_kernel<<<dim3(H_DIM / 256, T_TOKENS / 128, E_NUM), 512, 0, stream>>>(
      inter, w2b, cnt, base, list, y);
  combine_kernel<<<T_TOKENS, 256, 0, stream>>>(y, wpair, out);
}

// Round 14
// 727.144 us; speedup vs baseline: 1.0611x; 1.0611x over previous
//
#include <hip/hip_runtime.h>

// Problem constants (B=4, S=2048 -> T=8192)
#define T_TOKENS 8192
#define H_DIM 1024
#define F_DIM 4096
#define E_NUM 8

typedef unsigned short u16;
typedef __attribute__((ext_vector_type(8))) short bf16x8;
typedef __attribute__((ext_vector_type(4))) float f32x4;

__device__ __forceinline__ u16 f2bf(float f) {
  union { float f; unsigned int u; } v; v.f = f;
  unsigned int r = v.u + 0x7fffu + ((v.u >> 16) & 1u);
  return (u16)(r >> 16);
}
__device__ __forceinline__ float bf2f(u16 u) {
  union { unsigned int u; float f; } v; v.u = ((unsigned int)u) << 16;
  return v.f;
}

#define GLOAD_LDS(g, l)                                                        \
  __builtin_amdgcn_global_load_lds(                                            \
      (const __attribute__((address_space(1))) void*)(g),                      \
      (__attribute__((address_space(3))) void*)(l), 16, 0, 0)

// ---------------- fp32 -> bf16 convert (vectorized) ----------------
__global__ void cvt_kernel(const float* __restrict__ in, u16* __restrict__ out,
                           int n4) {
  int i = blockIdx.x * blockDim.x + threadIdx.x;
  int stride = gridDim.x * blockDim.x;
  for (; i < n4; i += stride) {
    float4 v = ((const float4*)in)[i];
    ushort4 o;
    o.x = f2bf(v.x); o.y = f2bf(v.y); o.z = f2bf(v.z); o.w = f2bf(v.w);
    ((ushort4*)out)[i] = o;
  }
}

// ------- router: logits + softmax + top2 + renorm, fused x->bf16 cvt -------
__global__ void router_kernel(const float* __restrict__ x,
                              const float* __restrict__ gw,
                              u16* __restrict__ xb,
                              float* __restrict__ logits_out,
                              int* __restrict__ sel, float* __restrict__ selw) {
  int wid = threadIdx.x >> 6;
  int lane = threadIdx.x & 63;
  int t = blockIdx.x * 4 + wid;
  const float4* xr = (const float4*)(x + (size_t)t * H_DIM);
  ushort4* xbr = (ushort4*)(xb + (size_t)t * H_DIM);
  float acc[E_NUM];
#pragma unroll
  for (int e = 0; e < E_NUM; e++) acc[e] = 0.f;
#pragma unroll
  for (int it = 0; it < H_DIM / 256; it++) {
    int i4 = it * 64 + lane;
    float4 v = xr[i4];
    ushort4 o;
    o.x = f2bf(v.x); o.y = f2bf(v.y); o.z = f2bf(v.z); o.w = f2bf(v.w);
    xbr[i4] = o;
#pragma unroll
    for (int e = 0; e < E_NUM; e++) {
      float4 g = ((const float4*)(gw + (size_t)e * H_DIM))[i4];
      acc[e] += v.x * g.x + v.y * g.y + v.z * g.z + v.w * g.w;
    }
  }
#pragma unroll
  for (int off = 32; off > 0; off >>= 1) {
#pragma unroll
    for (int e = 0; e < E_NUM; e++) acc[e] += __shfl_xor(acc[e], off);
  }
  if (lane < E_NUM) logits_out[(size_t)t * E_NUM + lane] = acc[lane];
  if (lane == 0) {
    float m = acc[0];
#pragma unroll
    for (int e = 1; e < E_NUM; e++) m = fmaxf(m, acc[e]);
    float p[E_NUM];
#pragma unroll
    for (int e = 0; e < E_NUM; e++) p[e] = expf(acc[e] - m);
    int e0 = 0; float p0 = p[0];
#pragma unroll
    for (int e = 1; e < E_NUM; e++) if (p[e] > p0) { p0 = p[e]; e0 = e; }
    int e1 = -1; float p1 = -1.f;
#pragma unroll
    for (int e = 0; e < E_NUM; e++)
      if (e != e0 && p[e] > p1) { p1 = p[e]; e1 = e; }
    float inv = 1.f / (p0 + p1);  // softmax denom cancels in renorm
    sel[t * 2] = e0; sel[t * 2 + 1] = e1;
    selw[t * 2] = p0 * inv; selw[t * 2 + 1] = p1 * inv;
  }
}

// ---------------- scatter: build per-expert pair lists ----------------
__global__ void scatter_kernel(const int* __restrict__ sel,
                               const float* __restrict__ selw,
                               int* __restrict__ cnt, int* __restrict__ list,
                               float* __restrict__ wpair) {
  int t = blockIdx.x * blockDim.x + threadIdx.x;
  if (t >= T_TOKENS) return;
#pragma unroll
  for (int k = 0; k < 2; k++) {
    int e = sel[t * 2 + k];
    int pos = atomicAdd(&cnt[e], 1);
    list[e * T_TOKENS + pos] = t * 2 + k;
    wpair[t * 2 + k] = selw[t * 2 + k];
  }
}

// ---------------- exclusive scan of expert counts (8 values) ----------------
__global__ void scan_kernel(const int* __restrict__ cnt, int* __restrict__ base) {
  if (threadIdx.x == 0) {
    int b = 0;
#pragma unroll
    for (int e = 0; e < E_NUM; e++) { base[e] = b; b += cnt[e]; }
  }
}

// ---- GEMM1: inter[base[e]+pos] = silu(x@w1^T) * (x@w3^T), compacted bf16 ---
// R8/R9/R12-proven: 128x128 tile, BK=64, 512 thr / 8 waves, wave-tile 32Mx64N.
// VGPR 64 + 64 AGPR -> 4 waves/SIMD, occ 41%, ~334us.
__global__ __launch_bounds__(512, 4) void gemm1_kernel(
    const u16* __restrict__ xb, const u16* __restrict__ w1b,
    const u16* __restrict__ w3b, const int* __restrict__ cnt,
    const int* __restrict__ base, const int* __restrict__ list,
    u16* __restrict__ inter) {
  int e = blockIdx.z;
  int ne = cnt[e];
  int m0 = blockIdx.y * 128;
  if (m0 >= ne) return;
  int nb = blockIdx.x;
  int cbase = base[e];

  __shared__ u16 al[128 * 64];
  __shared__ u16 b1l[128 * 64];
  __shared__ u16 b3l[128 * 64];
  __shared__ int s_pair[128];

  int tid = threadIdx.x;
  if (tid < 128) {
    int idx = m0 + tid;
    s_pair[tid] = list[e * T_TOKENS + (idx < ne ? idx : 0)];
  }
  __syncthreads();

  // staging: slot L = tid + 512*r covers row L>>3, 16B chunk L&7; source
  // chunk XOR-swizzled by row&7 so linear LDS dest ends up swizzled.
  const u16 *ab[2], *b1b[2], *b3b[2];
#pragma unroll
  for (int r = 0; r < 2; r++) {
    int L = tid + 512 * r;
    int row = L >> 3;
    int sc = (((L & 7) ^ (row & 7)) << 3);
    ab[r] = xb + (size_t)(s_pair[row] >> 1) * H_DIM + sc;
    b1b[r] = w1b + ((size_t)e * F_DIM + (size_t)nb * 128 + row) * H_DIM + sc;
    b3b[r] = w3b + ((size_t)e * F_DIM + (size_t)nb * 128 + row) * H_DIM + sc;
  }

  int lane = tid & 63, w = tid >> 6;
  int wm = (w & 3) * 32;   // 4 waves along M, 32 rows each
  int wn = (w >> 2) * 64;  // 2 waves along N, 64 cols each
  int fr = lane & 15, q0 = lane >> 4;

  f32x4 zero = {0.f, 0.f, 0.f, 0.f};
  f32x4 acc1[2][4], acc3[2][4];
#pragma unroll
  for (int i = 0; i < 2; i++)
#pragma unroll
    for (int j = 0; j < 4; j++) { acc1[i][j] = zero; acc3[i][j] = zero; }

  for (int kt = 0; kt < H_DIM; kt += 64) {
#pragma unroll
    for (int r = 0; r < 2; r++) {
      int c8 = (r * 512 + tid) * 8;
      GLOAD_LDS(ab[r] + kt, &al[c8]);
      GLOAD_LDS(b1b[r] + kt, &b1l[c8]);
      GLOAD_LDS(b3b[r] + kt, &b3l[c8]);
    }
    __syncthreads();
#pragma unroll
    for (int kk = 0; kk < 2; kk++) {
      int q = kk * 4 + q0;
      bf16x8 af[2], bf[4];
#pragma unroll
      for (int i = 0; i < 2; i++) {
        int row = wm + i * 16 + fr;
        af[i] = *(const bf16x8*)&al[row * 64 + ((q ^ (row & 7)) << 3)];
      }
#pragma unroll
      for (int j = 0; j < 4; j++) {
        int row = wn + j * 16 + fr;
        bf[j] = *(const bf16x8*)&b1l[row * 64 + ((q ^ (row & 7)) << 3)];
      }
#pragma unroll
      for (int i = 0; i < 2; i++)
#pragma unroll
        for (int j = 0; j < 4; j++)
          acc1[i][j] = __builtin_amdgcn_mfma_f32_16x16x32_bf16(
              af[i], bf[j], acc1[i][j], 0, 0, 0);
#pragma unroll
      for (int j = 0; j < 4; j++) {
        int row = wn + j * 16 + fr;
        bf[j] = *(const bf16x8*)&b3l[row * 64 + ((q ^ (row & 7)) << 3)];
      }
#pragma unroll
      for (int i = 0; i < 2; i++)
#pragma unroll
        for (int j = 0; j < 4; j++)
          acc3[i][j] = __builtin_amdgcn_mfma_f32_16x16x32_bf16(
              af[i], bf[j], acc3[i][j], 0, 0, 0);
    }
    __syncthreads();
  }

  // epilogue: SwiGLU, write compacted inter rows
#pragma unroll
  for (int i = 0; i < 2; i++) {
#pragma unroll
    for (int r = 0; r < 4; r++) {
      int ml = wm + i * 16 + q0 * 4 + r;
      if (m0 + ml < ne) {
        size_t basei =
            (size_t)(cbase + m0 + ml) * F_DIM + (size_t)nb * 128 + wn + fr;
#pragma unroll
        for (int j = 0; j < 4; j++) {
          float h1 = acc1[i][j][r], h3 = acc3[i][j][r];
          float v = h1 / (1.f + __expf(-h1)) * h3;
          inter[basei + j * 16] = f2bf(v);
        }
      }
    }
  }
}

// ---- GEMM2: y[pair] = inter[compact] @ w2^T (plain bf16 stores) ----
// R5-proven form: 128x128 tile, BK=64, 256 thr, 64x64 wave tiles. Six
// structural variants (dual-B x2, 512thr, BK=128, XCD-remap, atomics) all
// measured worse — this is gemm2's optimum under its small-N grid shape.
__global__ __launch_bounds__(256, 2) void gemm2_kernel(
    const u16* __restrict__ inter, const u16* __restrict__ w2b,
    const int* __restrict__ cnt, const int* __restrict__ base,
    const int* __restrict__ list, u16* __restrict__ y) {
  int e = blockIdx.z;
  int ne = cnt[e];
  int m0 = blockIdx.y * 128;
  if (m0 >= ne) return;
  int nb = blockIdx.x;  // H / 128
  int cbase = base[e];

  __shared__ u16 al[128 * 64];
  __shared__ u16 bl[128 * 64];
  __shared__ int s_pair[128];

  int tid = threadIdx.x;
  if (tid < 128) {
    int idx = m0 + tid;
    s_pair[tid] = list[e * T_TOKENS + (idx < ne ? idx : 0)];
  }
  __syncthreads();

  int sc = (((tid & 7) ^ ((tid >> 3) & 7)) << 3);
  const u16 *ab[4], *bb[4];
#pragma unroll
  for (int r = 0; r < 4; r++) {
    int row = r * 32 + (tid >> 3);
    int cr = m0 + row;
    if (cr >= ne) cr = 0;  // clamp within expert (stores guarded anyway)
    ab[r] = inter + (size_t)(cbase + cr) * F_DIM + sc;
    bb[r] = w2b + ((size_t)e * H_DIM + (size_t)nb * 128 + row) * F_DIM + sc;
  }

  int lane = tid & 63;
  int wm = ((tid >> 7) & 1) * 64;
  int wn = ((tid >> 6) & 1) * 64;
  f32x4 zero = {0.f, 0.f, 0.f, 0.f};
  f32x4 acc[4][4];
#pragma unroll
  for (int i = 0; i < 4; i++)
#pragma unroll
    for (int j = 0; j < 4; j++) acc[i][j] = zero;

  for (int kt = 0; kt < F_DIM; kt += 64) {
#pragma unroll
    for (int r = 0; r < 4; r++) {
      int c8 = (r * 256 + tid) * 8;
      GLOAD_LDS(ab[r] + kt, &al[c8]);
      GLOAD_LDS(bb[r] + kt, &bl[c8]);
    }
    __syncthreads();
#pragma unroll
    for (int kk = 0; kk < 2; kk++) {
      int q = kk * 4 + (lane >> 4);
      bf16x8 af[4], bf[4];
#pragma unroll
      for (int i = 0; i < 4; i++) {
        int row = wm + i * 16 + (lane & 15);
        af[i] = *(const bf16x8*)&al[row * 64 + ((q ^ (row & 7)) << 3)];
      }
#pragma unroll
      for (int j = 0; j < 4; j++) {
        int row = wn + j * 16 + (lane & 15);
        bf[j] = *(const bf16x8*)&bl[row * 64 + ((q ^ (row & 7)) << 3)];
      }
#pragma unroll
      for (int i = 0; i < 4; i++)
#pragma unroll
        for (int j = 0; j < 4; j++)
          acc[i][j] = __builtin_amdgcn_mfma_f32_16x16x32_bf16(
              af[i], bf[j], acc[i][j], 0, 0, 0);
    }
    __syncthreads();
  }

#pragma unroll
  for (int i = 0; i < 4; i++) {
#pragma unroll
    for (int r = 0; r < 4; r++) {
      int ml = wm + i * 16 + (lane >> 4) * 4 + r;
      if (m0 + ml < ne) {
        u16* yb =
            y + (size_t)s_pair[ml] * H_DIM + (size_t)nb * 128 + wn + (lane & 15);
#pragma unroll
        for (int j = 0; j < 4; j++) yb[j * 16] = f2bf(acc[i][j][r]);
      }
    }
  }
}

// ---- combine: out[t] = w0 * y[2t] + w1 * y[2t+1] (fp32 out) ----
__global__ void combine_kernel(const u16* __restrict__ y,
                               const float* __restrict__ wpair,
                               float* __restrict__ out) {
  int t = blockIdx.x;
  float w0 = wpair[t * 2], w1 = wpair[t * 2 + 1];
  const ushort4* y0 = (const ushort4*)(y + (size_t)t * 2 * H_DIM);
  const ushort4* y1 = (const ushort4*)(y + ((size_t)t * 2 + 1) * H_DIM);
  float4* o = (float4*)(out + (size_t)t * H_DIM);
  int i = threadIdx.x;  // 256 threads x 4 elems = 1024 = H_DIM
  ushort4 a = y0[i], b = y1[i];
  float4 r;
  r.x = w0 * bf2f(a.x) + w1 * bf2f(b.x);
  r.y = w0 * bf2f(a.y) + w1 * bf2f(b.y);
  r.z = w0 * bf2f(a.z) + w1 * bf2f(b.z);
  r.w = w0 * bf2f(a.w) + w1 * bf2f(b.w);
  o[i] = r;
}

// ---------------- workspace layout (bytes) ----------------
#define XB_OFF 0UL
#define W1B_OFF (XB_OFF + (size_t)T_TOKENS * H_DIM * 2)
#define W3B_OFF (W1B_OFF + (size_t)E_NUM * F_DIM * H_DIM * 2)
#define W2B_OFF (W3B_OFF + (size_t)E_NUM * F_DIM * H_DIM * 2)
#define INTER_OFF (W2B_OFF + (size_t)E_NUM * F_DIM * H_DIM * 2)
#define CNT_OFF (INTER_OFF + (size_t)2 * T_TOKENS * F_DIM * 2)
#define BASE_OFF (CNT_OFF + 64)
#define LIST_OFF (BASE_OFF + 192)
#define WPAIR_OFF (LIST_OFF + (size_t)E_NUM * T_TOKENS * 4)
#define SEL_OFF (WPAIR_OFF + (size_t)2 * T_TOKENS * 4)
#define SELW_OFF (SEL_OFF + (size_t)2 * T_TOKENS * 4)
// y (2T x H bf16, 32 MiB) aliases the dead w1b region (stream-ordered).
#define Y_OFF W1B_OFF

extern "C" void kernel_launch(void* const* d_in, const int* in_sizes, int n_in,
                              void* d_out, int out_size, void* d_ws,
                              size_t ws_size, hipStream_t stream) {
  const float* x = (const float*)d_in[0];
  const float* gw = (const float*)d_in[1];
  const float* w1 = (const float*)d_in[2];
  const float* w2 = (const float*)d_in[3];
  const float* w3 = (const float*)d_in[4];
  float* out = (float*)d_out;
  float* logits_out = out + (size_t)T_TOKENS * H_DIM;

  char* ws = (char*)d_ws;
  u16* xb = (u16*)(ws + XB_OFF);
  u16* w1b = (u16*)(ws + W1B_OFF);
  u16* w3b = (u16*)(ws + W3B_OFF);
  u16* w2b = (u16*)(ws + W2B_OFF);
  u16* inter = (u16*)(ws + INTER_OFF);
  u16* y = (u16*)(ws + Y_OFF);
  int* cnt = (int*)(ws + CNT_OFF);
  int* base = (int*)(ws + BASE_OFF);
  int* list = (int*)(ws + LIST_OFF);
  float* wpair = (float*)(ws + WPAIR_OFF);
  int* sel = (int*)(ws + SEL_OFF);
  float* selw = (float*)(ws + SELW_OFF);

  hipMemsetAsync(cnt, 0, 64, stream);

  cvt_kernel<<<2048, 256, 0, stream>>>(w1, w1b, E_NUM * F_DIM * H_DIM / 4);
  cvt_kernel<<<2048, 256, 0, stream>>>(w3, w3b, E_NUM * F_DIM * H_DIM / 4);
  cvt_kernel<<<2048, 256, 0, stream>>>(w2, w2b, E_NUM * F_DIM * H_DIM / 4);

  router_kernel<<<T_TOKENS / 4, 256, 0, stream>>>(x, gw, xb, logits_out, sel,
                                                  selw);
  scatter_kernel<<<T_TOKENS / 256, 256, 0, stream>>>(sel, selw, cnt, list,
                                                     wpair);
  scan_kernel<<<1, 64, 0, stream>>>(cnt, base);

  gemm1_kernel<<<dim3(F_DIM / 128, T_TOKENS / 128, E_NUM), 512, 0, stream>>>(
      xb, w1b, w3b, cnt, base, list, inter);
  gemm2_kernel<<<dim3(H_DIM / 128, T_TOKENS / 128, E_NUM), 256, 0, stream>>>(
      inter, w2b, cnt, base, list, y);
  combine_kernel<<<T_TOKENS, 256, 0, stream>>>(y, wpair, out);
}